// Round 6
// baseline (210.855 us; speedup 1.0000x reference)
//
#include <hip/hip_runtime.h>

// ResidualAttentionBlock (MFMA, round 6): B=16, FIN=256, H=W=32 (N=1024),
// NH=8, FH=64, CIN=258, COUT=512. Inputs fp32. All GEMMs on
// v_mfma_f32_16x16x32_bf16, fp32 accumulation.
//
// Round-6 changes vs round 5:
//  - attn computes S^T (A=K, B=Q) so P lands kt-adjacent per lane ->
//    packed ds_write_b64 into Pl[q][kt] (A-frag layout for GEMM2 O = P*V^T).
//    Kills the 4-way-conflicted 32x scalar P-writes (round-5 LDS hotspot).
//  - l is indexed by q=m15 -> one 2-shuffle reduction after the k-loop.
//  - 7 launches -> 4: prep = convw+xpose fused; qkv q/k/v fused (one launch,
//    mat from blockIdx.y; combined weight [1536][256] contiguous in ws).

typedef unsigned short u16;
typedef unsigned int   u32;
typedef __attribute__((ext_vector_type(8))) short  short8;
typedef __attribute__((ext_vector_type(4))) float  float4_;

#define MFMA16(a, b, c) __builtin_amdgcn_mfma_f32_16x16x32_bf16(a, b, c, 0, 0, 0)

__device__ __forceinline__ float bf2f(u16 u) {
    union { u32 i; float f; } v; v.i = ((u32)u) << 16; return v.f;
}
__device__ __forceinline__ u16 f2bf(float f) {           // RNE
    union { float f; u32 i; } v; v.f = f;
    u32 r = v.i + 0x7FFFu + ((v.i >> 16) & 1u);
    return (u16)(r >> 16);
}
__device__ __forceinline__ u16 f2bf_fast(float f) {      // round-half-up (f >= 0)
    union { float f; u32 i; } v; v.f = f;
    return (u16)((v.i + 0x8000u) >> 16);
}

// ---------------------------------------------------------------------------
// prep: blocks [0,512) convert wq/wk/wv [512][258] fp32 -> wb [1536][256] bf16
//       blocks [512,1536) transpose x [b][256][1024] fp32 -> xT [b][1024][256] bf16
// ---------------------------------------------------------------------------
__global__ __launch_bounds__(256) void prep(
    const float* __restrict__ wq, const float* __restrict__ wk,
    const float* __restrict__ wv, const float* __restrict__ x,
    u16* __restrict__ wb, u16* __restrict__ xT)
{
    __shared__ float Lt[64][65];
    const int bid = blockIdx.x;
    const int tid = threadIdx.x;
    if (bid < 512) {
        int i = bid * 256 + tid;             // [0, 131072)
        int o = i >> 8, c = i & 255;
        size_t si = (size_t)o * 258 + c;
        wb[i]          = f2bf(wq[si]);
        wb[131072 + i] = f2bf(wk[si]);
        wb[262144 + i] = f2bf(wv[si]);
    } else {
        int r = bid - 512;                   // [0, 1024)
        int n0 = (r & 15) * 64, c0 = ((r >> 4) & 3) * 64, b = r >> 6;
#pragma unroll
        for (int p = 0; p < 4; ++p) {
            int c = p * 16 + (tid >> 4);
            int nn = (tid & 15) * 4;
            float4 v = *(const float4*)&x[((size_t)(b * 256) + c0 + c) * 1024 + n0 + nn];
            Lt[c][nn + 0] = v.x; Lt[c][nn + 1] = v.y;
            Lt[c][nn + 2] = v.z; Lt[c][nn + 3] = v.w;
        }
        __syncthreads();
#pragma unroll
        for (int p = 0; p < 4; ++p) {
            int n = p * 16 + (tid >> 4);
            int cc = (tid & 15) * 4;
            ushort4 st;
            st.x = f2bf(Lt[cc + 0][n]); st.y = f2bf(Lt[cc + 1][n]);
            st.z = f2bf(Lt[cc + 2][n]); st.w = f2bf(Lt[cc + 3][n]);
            *(ushort4*)&xT[((size_t)(b << 10) + n0 + n) * 256 + c0 + cc] = st;
        }
    }
}

// ---------------------------------------------------------------------------
// Fused QKV GEMM: grid (16 nt, 24 mat*8+h, 16 b). [64 o][64 n] tile per block.
// mat 0=Q (token-major), 1=K (token-major, pre-scaled 1/8), 2=V (d-major).
// ---------------------------------------------------------------------------
__global__ __launch_bounds__(256) void qkv_mfma(
    const u16* __restrict__ xT, const u16* __restrict__ wb,
    const float* __restrict__ wq, const float* __restrict__ wk,
    const float* __restrict__ wv,
    const float* __restrict__ bq, const float* __restrict__ bk,
    const float* __restrict__ bv,
    u16* __restrict__ qkvbuf)
{
    __shared__ u16 Wl[64][72];
    __shared__ u16 Tl[64][72];
    const int tid = threadIdx.x;
    const int lane = tid & 63, w = tid >> 6;
    const int quad = lane >> 4, m15 = lane & 15;
    const int n0 = blockIdx.x * 64, by = blockIdx.y, b = blockIdx.z;
    const int mat = by >> 3, h = by & 7;
    const float* worig = (mat == 0) ? wq : ((mat == 1) ? wk : wv);
    const float* bias  = (mat == 0) ? bq : ((mat == 1) ? bk : bv);
    const float oscale = (mat == 1) ? 0.125f : 1.0f;
    const int wrow0 = mat * 512 + h * 64;
    u16* outbuf = qkvbuf + (size_t)mat * 8388608;

    float4_ acc[4] = {{0,0,0,0},{0,0,0,0},{0,0,0,0},{0,0,0,0}};
    const int row = tid >> 3, c8 = (tid & 7) * 8;

    for (int cc0 = 0; cc0 < 256; cc0 += 64) {
        __syncthreads();
#pragma unroll
        for (int rr = 0; rr < 64; rr += 32) {
            *(short8*)&Wl[row + rr][c8] =
                *(const short8*)(wb + (size_t)(wrow0 + row + rr) * 256 + cc0 + c8);
            *(short8*)&Tl[row + rr][c8] =
                *(const short8*)(xT + ((size_t)(b << 10) + n0 + row + rr) * 256 + cc0 + c8);
        }
        __syncthreads();
#pragma unroll
        for (int c = 0; c < 2; ++c) {
            short8 af = *(const short8*)&Wl[w * 16 + m15][c * 32 + quad * 8];
#pragma unroll
            for (int t = 0; t < 4; ++t) {
                short8 bf = *(const short8*)&Tl[t * 16 + m15][c * 32 + quad * 8];
                acc[t] = MFMA16(af, bf, acc[t]);
            }
        }
    }

    // rank-2 pos + bias, then scale. o_local = w*16 + quad*4 + r
    float wg[4], wx[4], bi[4];
#pragma unroll
    for (int r = 0; r < 4; ++r) {
        int o = h * 64 + w * 16 + quad * 4 + r;
        wg[r] = worig[(size_t)o * 258 + 256];
        wx[r] = worig[(size_t)o * 258 + 257];
        bi[r] = bias[o];
    }
#pragma unroll
    for (int t = 0; t < 4; ++t) {
        int n = n0 + t * 16 + m15;
        float gy = -1.0f + 2.0f * (float)(n >> 5) / 31.0f;
        float gx = -1.0f + 2.0f * (float)(n & 31) / 31.0f;
#pragma unroll
        for (int r = 0; r < 4; ++r)
            acc[t][r] = (acc[t][r] + wg[r] * gy + wx[r] * gx + bi[r]) * oscale;
    }

    if (mat != 2) {  // token-major [bh][n][64]
#pragma unroll
        for (int t = 0; t < 4; ++t) {
            int n = n0 + t * 16 + m15;
            ushort4 st;
            st.x = f2bf(acc[t][0]); st.y = f2bf(acc[t][1]);
            st.z = f2bf(acc[t][2]); st.w = f2bf(acc[t][3]);
            *(ushort4*)&outbuf[((size_t)(b * 8 + h) * 1024 + n) * 64 + w * 16 + quad * 4] = st;
        }
    } else {         // d-major [bh][64][n] (V)
#pragma unroll
        for (int t = 0; t < 4; ++t) {
            int n = n0 + t * 16 + m15;
#pragma unroll
            for (int r = 0; r < 4; ++r) {
                int d = w * 16 + quad * 4 + r;
                outbuf[((size_t)(b * 8 + h) * 64 + d) * 1024 + n] = f2bf(acc[t][r]);
            }
        }
    }
}

// ---------------------------------------------------------------------------
// Attention: block = (bh, q-tile 128), 4 waves x 2 q-subs of 16 rows.
// GEMM1 computes S^T (A=K,B=Q) -> P packed b64 into Pl[q][kt] (A-frag layout)
// -> GEMM2 O = P * V^T directly. No-max softmax; l reduced once post-loop.
// Grid (8 qt, 128 bh).
// ---------------------------------------------------------------------------
__global__ __launch_bounds__(256) void attn_mfma(
    const u16* __restrict__ qbuf, const u16* __restrict__ kbuf,
    const u16* __restrict__ vbuf, u16* __restrict__ ao)
{
    __shared__ u16 Kl[64][72];       // [kt][d]
    __shared__ u16 Vl[64][72];       // V^T: [d][kt]
    __shared__ u16 Pl[4][32][72];    // per-wave P [q_local][kt]

    const int tid = threadIdx.x;
    const int lane = tid & 63, w = tid >> 6;
    const int quad = lane >> 4, m15 = lane & 15;
    const int q0 = blockIdx.x * 128;
    const int bh = blockIdx.y;
    const u16* qb = qbuf + (size_t)bh * 65536;
    const u16* kb = kbuf + (size_t)bh * 65536;
    const u16* vb = vbuf + (size_t)bh * 65536;   // [64 d][1024 n]

    // Q B-frags for both subs (B layout [n=m15 -> q][k=quad*8+j -> d])
    short8 qf[2][2];
#pragma unroll
    for (int s = 0; s < 2; ++s) {
        const u16* qr = qb + (size_t)(q0 + w * 32 + s * 16 + m15) * 64 + quad * 8;
        qf[s][0] = *(const short8*)qr;
        qf[s][1] = *(const short8*)(qr + 32);
    }

    float4_ O[2][4];                 // O[q][d] tiles: row=q_local, col=d
    float lp[2] = {0.0f, 0.0f};      // partial l for q = m15 (per sub)
#pragma unroll
    for (int s = 0; s < 2; ++s)
#pragma unroll
        for (int t = 0; t < 4; ++t) O[s][t] = (float4_){0, 0, 0, 0};

    const int row = tid >> 3, c8 = (tid & 7) * 8;

    for (int kt0 = 0; kt0 < 1024; kt0 += 64) {
        __syncthreads();
#pragma unroll
        for (int rr = 0; rr < 64; rr += 32) {
            *(short8*)&Kl[row + rr][c8] =
                *(const short8*)(kb + (size_t)(kt0 + row + rr) * 64 + c8);
            *(short8*)&Vl[row + rr][c8] =
                *(const short8*)(vb + (size_t)(row + rr) * 1024 + kt0 + c8);
        }
        __syncthreads();

        // GEMM1: S^T[kt][q]  (A=K [m=kt][k=d], B=Q [n=q][k=d]; K pre-scaled 1/8)
        float4_ S[2][4];
#pragma unroll
        for (int s = 0; s < 2; ++s)
#pragma unroll
            for (int t = 0; t < 4; ++t) S[s][t] = (float4_){0, 0, 0, 0};
#pragma unroll
        for (int c = 0; c < 2; ++c) {
            short8 kf[4];
#pragma unroll
            for (int t = 0; t < 4; ++t)
                kf[t] = *(const short8*)&Kl[t * 16 + m15][c * 32 + quad * 8];
#pragma unroll
            for (int s = 0; s < 2; ++s)
#pragma unroll
                for (int t = 0; t < 4; ++t)
                    S[s][t] = MFMA16(kf[t], qf[s][c], S[s][t]);
        }

        // exp + packed P write (kt-adjacent regs -> one b64 per (s,t)) + l partial
#pragma unroll
        for (int s = 0; s < 2; ++s) {
#pragma unroll
            for (int t = 0; t < 4; ++t) {
                float p0 = __expf(S[s][t][0]);
                float p1 = __expf(S[s][t][1]);
                float p2 = __expf(S[s][t][2]);
                float p3 = __expf(S[s][t][3]);
                ushort4 pk;
                pk.x = f2bf_fast(p0); pk.y = f2bf_fast(p1);
                pk.z = f2bf_fast(p2); pk.w = f2bf_fast(p3);
                *(ushort4*)&Pl[w][s * 16 + m15][t * 16 + quad * 4] = pk;
                lp[s] += (p0 + p1) + (p2 + p3);
            }
        }

        // GEMM2: O[q][d] += P[q][kt] * V^T[d][kt]  (Pl per-wave: no barrier)
#pragma unroll
        for (int c = 0; c < 2; ++c) {
            short8 vf[4];
#pragma unroll
            for (int dt = 0; dt < 4; ++dt)
                vf[dt] = *(const short8*)&Vl[dt * 16 + m15][c * 32 + quad * 8];
#pragma unroll
            for (int s = 0; s < 2; ++s) {
                short8 pf = *(const short8*)&Pl[w][s * 16 + m15][c * 32 + quad * 8];
#pragma unroll
                for (int dt = 0; dt < 4; ++dt)
                    O[s][dt] = MFMA16(pf, vf[dt], O[s][dt]);
            }
        }
    }

    // reduce l over the 4 quads (lanes sharing m15), once
#pragma unroll
    for (int s = 0; s < 2; ++s) {
        float v = lp[s];
        v += __shfl_xor(v, 16);
        v += __shfl_xor(v, 32);
        lp[s] = v;   // all lanes now hold full l for q = m15 (sub s)
    }

    const int b = bh >> 3, h = bh & 7;
#pragma unroll
    for (int s = 0; s < 2; ++s) {
        float li[4];
#pragma unroll
        for (int r = 0; r < 4; ++r)
            li[r] = 1.0f / __shfl(lp[s], quad * 4 + r);   // l for row q=quad*4+r
#pragma unroll
        for (int dt = 0; dt < 4; ++dt)
#pragma unroll
            for (int r = 0; r < 4; ++r) {
                int n = q0 + w * 32 + s * 16 + quad * 4 + r;
                ao[((size_t)(b << 10) + n) * 512 + h * 64 + dt * 16 + m15] =
                    f2bf(O[s][dt][r] * li[r]);
            }
    }
}

// ---------------------------------------------------------------------------
// Output projection + bias + residual (fp32 out, wo converted during staging).
// Grid (16 nt, 4 ft, 16 b).
// ---------------------------------------------------------------------------
__global__ __launch_bounds__(256) void proj_mfma(
    const u16* __restrict__ ao, const float* __restrict__ wo,
    const float* __restrict__ bo, const float* __restrict__ x,
    float* __restrict__ out)
{
    __shared__ u16 Wl[64][72];
    __shared__ u16 Tl[64][72];
    const int tid = threadIdx.x;
    const int lane = tid & 63, w = tid >> 6;
    const int quad = lane >> 4, m15 = lane & 15;
    const int n0 = blockIdx.x * 64, f0 = blockIdx.y * 64, b = blockIdx.z;

    float4_ acc[4] = {{0,0,0,0},{0,0,0,0},{0,0,0,0},{0,0,0,0}};
    const int row = tid >> 3, c8 = (tid & 7) * 8;

    for (int cc0 = 0; cc0 < 512; cc0 += 64) {
        __syncthreads();
#pragma unroll
        for (int rr = 0; rr < 64; rr += 32) {
            const float* wsrc = wo + (size_t)(f0 + row + rr) * 512 + cc0 + c8;
            float4 v0 = *(const float4*)wsrc;
            float4 v1 = *(const float4*)(wsrc + 4);
            ushort4 s0, s1;
            s0.x = f2bf(v0.x); s0.y = f2bf(v0.y); s0.z = f2bf(v0.z); s0.w = f2bf(v0.w);
            s1.x = f2bf(v1.x); s1.y = f2bf(v1.y); s1.z = f2bf(v1.z); s1.w = f2bf(v1.w);
            *(ushort4*)&Wl[row + rr][c8]     = s0;
            *(ushort4*)&Wl[row + rr][c8 + 4] = s1;
            *(short8*)&Tl[row + rr][c8] =
                *(const short8*)(ao + ((size_t)(b << 10) + n0 + row + rr) * 512 + cc0 + c8);
        }
        __syncthreads();
#pragma unroll
        for (int c = 0; c < 2; ++c) {
            short8 af = *(const short8*)&Wl[w * 16 + m15][c * 32 + quad * 8];
#pragma unroll
            for (int t = 0; t < 4; ++t) {
                short8 bf = *(const short8*)&Tl[t * 16 + m15][c * 32 + quad * 8];
                acc[t] = MFMA16(af, bf, acc[t]);
            }
        }
    }

    float bi[4];
#pragma unroll
    for (int r = 0; r < 4; ++r) bi[r] = bo[f0 + w * 16 + quad * 4 + r];
#pragma unroll
    for (int t = 0; t < 4; ++t) {
        int n = n0 + t * 16 + m15;
#pragma unroll
        for (int r = 0; r < 4; ++r) {
            int f = f0 + w * 16 + quad * 4 + r;
            size_t idx = ((size_t)(b * 256) + f) * 1024 + n;
            out[idx] = acc[t][r] + bi[r] + x[idx];
        }
    }
}

extern "C" void kernel_launch(void* const* d_in, const int* in_sizes, int n_in,
                              void* d_out, int out_size, void* d_ws, size_t ws_size,
                              hipStream_t stream) {
    const float* x  = (const float*)d_in[0];
    const float* wq = (const float*)d_in[1];
    const float* bq = (const float*)d_in[2];
    const float* wk = (const float*)d_in[3];
    const float* bk = (const float*)d_in[4];
    const float* wv = (const float*)d_in[5];
    const float* bv = (const float*)d_in[6];
    const float* wo = (const float*)d_in[7];
    const float* bo = (const float*)d_in[8];

    // ws layout (u16 elems), 64 MiB total:
    //   qkvbuf: 3 x 8,388,608 (Q, K, V contiguous)
    //   region: xT[4,194,304] + wb[393,216] (combined [1536][256])
    //   ao aliases region (everything there dead after qkv kernel).
    u16* qkvbuf = (u16*)d_ws;
    u16* region = qkvbuf + 3 * 8388608;
    u16* xT = region;
    u16* wb = region + 4194304;
    u16* aobf = region;   // alias, written only after qkv done

    prep<<<1536, 256, 0, stream>>>(wq, wk, wv, x, wb, xT);

    qkv_mfma<<<dim3(16, 24, 16), 256, 0, stream>>>(
        xT, wb, wq, wk, wv, bq, bk, bv, qkvbuf);

    attn_mfma<<<dim3(8, 128), 256, 0, stream>>>(
        qkvbuf, qkvbuf + 8388608, qkvbuf + 16777216, aobf);

    proj_mfma<<<dim3(16, 4, 16), 256, 0, stream>>>(aobf, wo, bo, x, (float*)d_out);
}

// Round 7
// 202.446 us; speedup vs baseline: 1.0415x; 1.0415x over previous
//
#include <hip/hip_runtime.h>

// ResidualAttentionBlock (MFMA, round 7): B=16, FIN=256, H=W=32 (N=1024),
// NH=8, FH=64, CIN=258, COUT=512. Inputs fp32. v_mfma_f32_16x16x32_bf16,
// fp32 accumulation.
//
// Round 7:
//  - attn main loop reverted to the proven round-5 version (round-6 S^T
//    restructure regressed: conflicts UP, MfmaUtil down). Epilogue now writes
//    AO in [bh][n][64] IN-PLACE over qbuf (each block reads only its own Q
//    rows before writing them) -> no ws aliasing, proj reads contiguous-64.
//  - qkv: 128x128 tile, BK=32 (20.5 KB LDS): 0.875 b128/MFMA vs 1.75 for the
//    old 64-tile -> halves qkv LDS-pipe cost. Single fused launch.
//  - proj unchanged except AO indexing.

typedef unsigned short u16;
typedef unsigned int   u32;
typedef __attribute__((ext_vector_type(8))) short  short8;
typedef __attribute__((ext_vector_type(4))) float  float4_;

#define MFMA16(a, b, c) __builtin_amdgcn_mfma_f32_16x16x32_bf16(a, b, c, 0, 0, 0)

__device__ __forceinline__ float bf2f(u16 u) {
    union { u32 i; float f; } v; v.i = ((u32)u) << 16; return v.f;
}
__device__ __forceinline__ u16 f2bf(float f) {           // RNE
    union { float f; u32 i; } v; v.f = f;
    u32 r = v.i + 0x7FFFu + ((v.i >> 16) & 1u);
    return (u16)(r >> 16);
}
__device__ __forceinline__ u16 f2bf_fast(float f) {      // round-half-up (f >= 0)
    union { float f; u32 i; } v; v.f = f;
    return (u16)((v.i + 0x8000u) >> 16);
}

// ---------------------------------------------------------------------------
// prep: blocks [0,512) convert wq/wk/wv [512][258] fp32 -> wb [1536][256] bf16
//       blocks [512,1536) transpose x [b][256][1024] fp32 -> xT [b][1024][256]
// ---------------------------------------------------------------------------
__global__ __launch_bounds__(256) void prep(
    const float* __restrict__ wq, const float* __restrict__ wk,
    const float* __restrict__ wv, const float* __restrict__ x,
    u16* __restrict__ wb, u16* __restrict__ xT)
{
    __shared__ float Lt[64][65];
    const int bid = blockIdx.x;
    const int tid = threadIdx.x;
    if (bid < 512) {
        int i = bid * 256 + tid;
        int o = i >> 8, c = i & 255;
        size_t si = (size_t)o * 258 + c;
        wb[i]          = f2bf(wq[si]);
        wb[131072 + i] = f2bf(wk[si]);
        wb[262144 + i] = f2bf(wv[si]);
    } else {
        int r = bid - 512;
        int n0 = (r & 15) * 64, c0 = ((r >> 4) & 3) * 64, b = r >> 6;
#pragma unroll
        for (int p = 0; p < 4; ++p) {
            int c = p * 16 + (tid >> 4);
            int nn = (tid & 15) * 4;
            float4 v = *(const float4*)&x[((size_t)(b * 256) + c0 + c) * 1024 + n0 + nn];
            Lt[c][nn + 0] = v.x; Lt[c][nn + 1] = v.y;
            Lt[c][nn + 2] = v.z; Lt[c][nn + 3] = v.w;
        }
        __syncthreads();
#pragma unroll
        for (int p = 0; p < 4; ++p) {
            int n = p * 16 + (tid >> 4);
            int cc = (tid & 15) * 4;
            ushort4 st;
            st.x = f2bf(Lt[cc + 0][n]); st.y = f2bf(Lt[cc + 1][n]);
            st.z = f2bf(Lt[cc + 2][n]); st.w = f2bf(Lt[cc + 3][n]);
            *(ushort4*)&xT[((size_t)(b << 10) + n0 + n) * 256 + c0 + cc] = st;
        }
    }
}

// ---------------------------------------------------------------------------
// Fused QKV GEMM, 128x128 tile, BK=32. Grid (8 nt, 12 mt, 16 b).
// mt covers 128 rows of the combined [1536][256] weight: mat = mt>>2,
// heads h0=(mt&3)*2, h0+1. mat 0=Q, 1=K (pre-scaled 1/8) token-major
// [bh][n][64]; mat 2=V d-major [bh][64][n].
// ---------------------------------------------------------------------------
__global__ __launch_bounds__(256) void qkv_mfma(
    const u16* __restrict__ xT, const u16* __restrict__ wb,
    const float* __restrict__ wq, const float* __restrict__ wk,
    const float* __restrict__ wv,
    const float* __restrict__ bq, const float* __restrict__ bk,
    const float* __restrict__ bv,
    u16* __restrict__ qkvbuf)
{
    __shared__ u16 Wl[128][40];
    __shared__ u16 Tl[128][40];
    const int tid = threadIdx.x;
    const int lane = tid & 63, w = tid >> 6;
    const int quad = lane >> 4, m15 = lane & 15;
    const int n0 = blockIdx.x * 128, mt = blockIdx.y, b = blockIdx.z;
    const int mat = mt >> 2;
    const int m0 = mt * 128;                    // row in combined W
    const float* worig = (mat == 0) ? wq : ((mat == 1) ? wk : wv);
    const float* bias  = (mat == 0) ? bq : ((mat == 1) ? bk : bv);
    const float oscale = (mat == 1) ? 0.125f : 1.0f;
    u16* outbuf = qkvbuf + (size_t)mat * 8388608;

    float4_ acc[2][8];
#pragma unroll
    for (int s = 0; s < 2; ++s)
#pragma unroll
        for (int t = 0; t < 8; ++t) acc[s][t] = (float4_){0, 0, 0, 0};

    const int row = tid >> 2, col8 = (tid & 3) * 8;   // 64 rows x 32 cols per pass

    for (int cc0 = 0; cc0 < 256; cc0 += 32) {
        __syncthreads();
#pragma unroll
        for (int rr = 0; rr < 128; rr += 64) {
            *(short8*)&Wl[row + rr][col8] =
                *(const short8*)(wb + (size_t)(m0 + row + rr) * 256 + cc0 + col8);
            *(short8*)&Tl[row + rr][col8] =
                *(const short8*)(xT + ((size_t)(b << 10) + n0 + row + rr) * 256 + cc0 + col8);
        }
        __syncthreads();
        short8 af[2];
#pragma unroll
        for (int s = 0; s < 2; ++s)
            af[s] = *(const short8*)&Wl[w * 32 + s * 16 + m15][quad * 8];
#pragma unroll
        for (int t = 0; t < 8; ++t) {
            short8 bf = *(const short8*)&Tl[t * 16 + m15][quad * 8];
#pragma unroll
            for (int s = 0; s < 2; ++s)
                acc[s][t] = MFMA16(af[s], bf, acc[s][t]);
        }
    }

    // epilogue: rank-2 pos + bias, scale, store. om = row within this mat's 512.
#pragma unroll
    for (int s = 0; s < 2; ++s) {
        float wg[4], wx[4], bi[4];
#pragma unroll
        for (int r = 0; r < 4; ++r) {
            int om = (mt & 3) * 128 + w * 32 + s * 16 + quad * 4 + r;
            wg[r] = worig[(size_t)om * 258 + 256];
            wx[r] = worig[(size_t)om * 258 + 257];
            bi[r] = bias[om];
        }
        const int h = (mt & 3) * 2 + ((w * 32 + s * 16) >> 6);
        const int dbase = ((w * 32 + s * 16) & 63) + quad * 4;
#pragma unroll
        for (int t = 0; t < 8; ++t) {
            int n = n0 + t * 16 + m15;
            float gy = -1.0f + 2.0f * (float)(n >> 5) / 31.0f;
            float gx = -1.0f + 2.0f * (float)(n & 31) / 31.0f;
            float v[4];
#pragma unroll
            for (int r = 0; r < 4; ++r)
                v[r] = (acc[s][t][r] + wg[r] * gy + wx[r] * gx + bi[r]) * oscale;
            if (mat != 2) {      // token-major [bh][n][64]
                ushort4 st;
                st.x = f2bf(v[0]); st.y = f2bf(v[1]);
                st.z = f2bf(v[2]); st.w = f2bf(v[3]);
                *(ushort4*)&outbuf[((size_t)(b * 8 + h) * 1024 + n) * 64 + dbase] = st;
            } else {             // d-major [bh][64][n]
#pragma unroll
                for (int r = 0; r < 4; ++r)
                    outbuf[((size_t)(b * 8 + h) * 64 + dbase + r) * 1024 + n] = f2bf(v[r]);
            }
        }
    }
}

// ---------------------------------------------------------------------------
// Attention (round-5 proven loop): block = (bh, q-tile 128), 4 waves x 2 subs.
// No-max softmax, l reduced once post-loop. Output written IN-PLACE over
// qbuf in [bh][n][64] layout. Grid (8 qt, 128 bh).
// ---------------------------------------------------------------------------
__global__ __launch_bounds__(256) void attn_mfma(
    u16* __restrict__ qbuf, const u16* __restrict__ kbuf,
    const u16* __restrict__ vbuf)
{
    __shared__ u16 Kl[64][72];       // [kt][d]
    __shared__ u16 Vl[64][72];       // V^T: [d][kt]
    __shared__ u16 Pl[4][32][72];    // per-wave P [q_local][kt] bf16

    const int tid = threadIdx.x;
    const int lane = tid & 63, w = tid >> 6;
    const int quad = lane >> 4, m15 = lane & 15;
    const int q0 = blockIdx.x * 128;
    const int bh = blockIdx.y;
    u16* qb = qbuf + (size_t)bh * 65536;
    const u16* kb = kbuf + (size_t)bh * 65536;
    const u16* vb = vbuf + (size_t)bh * 65536;   // [64 d][1024 n]

    // Q A-frags for both sub-tiles (persist across k-loop)
    short8 qf[2][2];
#pragma unroll
    for (int s = 0; s < 2; ++s) {
        const u16* qr = qb + (size_t)(q0 + w * 32 + s * 16 + m15) * 64 + quad * 8;
        qf[s][0] = *(const short8*)qr;
        qf[s][1] = *(const short8*)(qr + 32);
    }

    float4_ O[2][4];                 // O^T tiles per sub
    float lp[2][4];                  // per-lane partial l
#pragma unroll
    for (int s = 0; s < 2; ++s)
#pragma unroll
        for (int t = 0; t < 4; ++t) { O[s][t] = (float4_){0,0,0,0}; lp[s][t] = 0.0f; }

    const int row = tid >> 3, c8 = (tid & 7) * 8;

    for (int kt0 = 0; kt0 < 1024; kt0 += 64) {
        __syncthreads();
#pragma unroll
        for (int rr = 0; rr < 64; rr += 32) {
            *(short8*)&Kl[row + rr][c8] =
                *(const short8*)(kb + (size_t)(kt0 + row + rr) * 64 + c8);
            *(short8*)&Vl[row + rr][c8] =
                *(const short8*)(vb + (size_t)(row + rr) * 1024 + kt0 + c8);
        }
        __syncthreads();

        // GEMM1: S[s][t], q_local = quad*4+r, kt = t*16+m15 (K pre-scaled 1/8)
        float4_ S[2][4];
#pragma unroll
        for (int s = 0; s < 2; ++s)
#pragma unroll
            for (int t = 0; t < 4; ++t) S[s][t] = (float4_){0, 0, 0, 0};
#pragma unroll
        for (int c = 0; c < 2; ++c) {
            short8 bk[4];
#pragma unroll
            for (int t = 0; t < 4; ++t)
                bk[t] = *(const short8*)&Kl[t * 16 + m15][c * 32 + quad * 8];
#pragma unroll
            for (int s = 0; s < 2; ++s)
#pragma unroll
                for (int t = 0; t < 4; ++t)
                    S[s][t] = MFMA16(qf[s][c], bk[t], S[s][t]);
        }

        // exp (no max-shift) + P write + l partial
#pragma unroll
        for (int s = 0; s < 2; ++s)
#pragma unroll
            for (int r = 0; r < 4; ++r) {
                float p0 = __expf(S[s][0][r]);
                float p1 = __expf(S[s][1][r]);
                float p2 = __expf(S[s][2][r]);
                float p3 = __expf(S[s][3][r]);
                u16* pr = &Pl[w][s * 16 + quad * 4 + r][m15];
                pr[0]  = f2bf_fast(p0);
                pr[16] = f2bf_fast(p1);
                pr[32] = f2bf_fast(p2);
                pr[48] = f2bf_fast(p3);
                lp[s][r] += (p0 + p1) + (p2 + p3);
            }

        // GEMM2: O^T[d][q'] += V^T[d][kt] * P^T[kt][q']  (Pl per-wave)
#pragma unroll
        for (int c = 0; c < 2; ++c) {
            short8 av[4];
#pragma unroll
            for (int dt = 0; dt < 4; ++dt)
                av[dt] = *(const short8*)&Vl[dt * 16 + m15][c * 32 + quad * 8];
#pragma unroll
            for (int s = 0; s < 2; ++s) {
                short8 bp = *(const short8*)&Pl[w][s * 16 + m15][c * 32 + quad * 8];
#pragma unroll
                for (int dt = 0; dt < 4; ++dt)
                    O[s][dt] = MFMA16(av[dt], bp, O[s][dt]);
            }
        }
    }

    // reduce l across the 16 lanes of each quad group (once)
#pragma unroll
    for (int s = 0; s < 2; ++s)
#pragma unroll
        for (int r = 0; r < 4; ++r) {
            float v = lp[s][r];
            v += __shfl_xor(v, 1);
            v += __shfl_xor(v, 2);
            v += __shfl_xor(v, 4);
            v += __shfl_xor(v, 8);
            lp[s][r] = v;
        }

#pragma unroll
    for (int s = 0; s < 2; ++s) {
        // broadcast l[q'=m15] from the group holding that q row
        int src = (m15 >> 2) * 16;
        float a0 = __shfl(lp[s][0], src);
        float a1 = __shfl(lp[s][1], src);
        float a2 = __shfl(lp[s][2], src);
        float a3 = __shfl(lp[s][3], src);
        int rr2 = m15 & 3;
        float lq = (rr2 & 2) ? ((rr2 & 1) ? a3 : a2) : ((rr2 & 1) ? a1 : a0);
        float linv = 1.0f / lq;
        int n = q0 + w * 32 + s * 16 + m15;
#pragma unroll
        for (int dt = 0; dt < 4; ++dt) {
            ushort4 st;
            st.x = f2bf(O[s][dt][0] * linv);
            st.y = f2bf(O[s][dt][1] * linv);
            st.z = f2bf(O[s][dt][2] * linv);
            st.w = f2bf(O[s][dt][3] * linv);
            // in-place over qbuf: [bh][n][64]
            *(ushort4*)&qb[(size_t)n * 64 + dt * 16 + quad * 4] = st;
        }
    }
}

// ---------------------------------------------------------------------------
// Output projection + bias + residual. AO read from qbuf [bh][n][64].
// Grid (16 nt, 4 ft, 16 b).
// ---------------------------------------------------------------------------
__global__ __launch_bounds__(256) void proj_mfma(
    const u16* __restrict__ ao, const float* __restrict__ wo,
    const float* __restrict__ bo, const float* __restrict__ x,
    float* __restrict__ out)
{
    __shared__ u16 Wl[64][72];
    __shared__ u16 Tl[64][72];
    const int tid = threadIdx.x;
    const int lane = tid & 63, w = tid >> 6;
    const int quad = lane >> 4, m15 = lane & 15;
    const int n0 = blockIdx.x * 64, f0 = blockIdx.y * 64, b = blockIdx.z;

    float4_ acc[4] = {{0,0,0,0},{0,0,0,0},{0,0,0,0},{0,0,0,0}};
    const int row = tid >> 3, c8 = (tid & 7) * 8;

    for (int cc0 = 0; cc0 < 512; cc0 += 64) {
        __syncthreads();
        const int h = cc0 >> 6;
#pragma unroll
        for (int rr = 0; rr < 64; rr += 32) {
            const float* wsrc = wo + (size_t)(f0 + row + rr) * 512 + cc0 + c8;
            float4 v0 = *(const float4*)wsrc;
            float4 v1 = *(const float4*)(wsrc + 4);
            ushort4 s0, s1;
            s0.x = f2bf(v0.x); s0.y = f2bf(v0.y); s0.z = f2bf(v0.z); s0.w = f2bf(v0.w);
            s1.x = f2bf(v1.x); s1.y = f2bf(v1.y); s1.z = f2bf(v1.z); s1.w = f2bf(v1.w);
            *(ushort4*)&Wl[row + rr][c8]     = s0;
            *(ushort4*)&Wl[row + rr][c8 + 4] = s1;
            *(short8*)&Tl[row + rr][c8] =
                *(const short8*)(ao + ((size_t)((b << 3) + h) * 1024 + n0 + row + rr) * 64 + c8);
        }
        __syncthreads();
#pragma unroll
        for (int c = 0; c < 2; ++c) {
            short8 af = *(const short8*)&Wl[w * 16 + m15][c * 32 + quad * 8];
#pragma unroll
            for (int t = 0; t < 4; ++t) {
                short8 bf = *(const short8*)&Tl[t * 16 + m15][c * 32 + quad * 8];
                acc[t] = MFMA16(af, bf, acc[t]);
            }
        }
    }

    float bi[4];
#pragma unroll
    for (int r = 0; r < 4; ++r) bi[r] = bo[f0 + w * 16 + quad * 4 + r];
#pragma unroll
    for (int t = 0; t < 4; ++t) {
        int n = n0 + t * 16 + m15;
#pragma unroll
        for (int r = 0; r < 4; ++r) {
            int f = f0 + w * 16 + quad * 4 + r;
            size_t idx = ((size_t)(b * 256) + f) * 1024 + n;
            out[idx] = acc[t][r] + bi[r] + x[idx];
        }
    }
}

extern "C" void kernel_launch(void* const* d_in, const int* in_sizes, int n_in,
                              void* d_out, int out_size, void* d_ws, size_t ws_size,
                              hipStream_t stream) {
    const float* x  = (const float*)d_in[0];
    const float* wq = (const float*)d_in[1];
    const float* bq = (const float*)d_in[2];
    const float* wk = (const float*)d_in[3];
    const float* bk = (const float*)d_in[4];
    const float* wv = (const float*)d_in[5];
    const float* bv = (const float*)d_in[6];
    const float* wo = (const float*)d_in[7];
    const float* bo = (const float*)d_in[8];

    // ws layout (u16 elems), ~59.8 MiB used:
    //   qkvbuf: 3 x 8,388,608 (Q, K, V). attn writes AO in-place over Q.
    //   region: xT[4,194,304] + wb[393,216] — no aliasing with anything live.
    u16* qkvbuf = (u16*)d_ws;
    u16* region = qkvbuf + 3 * 8388608;
    u16* xT = region;
    u16* wb = region + 4194304;

    prep<<<1536, 256, 0, stream>>>(wq, wk, wv, x, wb, xT);

    qkv_mfma<<<dim3(8, 12, 16), 256, 0, stream>>>(
        xT, wb, wq, wk, wv, bq, bk, bv, qkvbuf);

    attn_mfma<<<dim3(8, 128), 256, 0, stream>>>(
        qkvbuf, qkvbuf + 8388608, qkvbuf + 16777216);

    proj_mfma<<<dim3(16, 4, 16), 256, 0, stream>>>(qkvbuf, wo, bo, x, (float*)d_out);
}